// Round 2
// baseline (265.955 us; speedup 1.0000x reference)
//
#include <hip/hip_runtime.h>
#include <math.h>
#include <stdint.h>

#define BATCH 64
#define SEQ   101
#define HID   512
#define NKQ   100      // N*K
#define KCLS  10
#define INV_TEMP 0.04419417382415922f   // 1/sqrt(512)

typedef short bf16x8 __attribute__((ext_vector_type(8)));
typedef float f32x4  __attribute__((ext_vector_type(4)));
typedef uint32_t u32x4 __attribute__((ext_vector_type(4)));

// HW packed f32->bf16 RNE: dst.lo = bf16(a), dst.hi = bf16(b)
__device__ inline uint32_t cvt2(float a, float b) {
    uint32_t r;
    asm("v_cvt_pk_bf16_f32 %0, %1, %2" : "=v"(r) : "v"(a), "v"(b));
    return r;
}
// truncation split: x == hi + lo to ~2^-17 rel (q & P planes, as in prev rounds)
__device__ inline void split_bf16(float x, short& hi, short& lo) {
    uint32_t u = __builtin_bit_cast(uint32_t, x);
    hi = (short)(u >> 16);
    float hf = __builtin_bit_cast(float, u & 0xFFFF0000u);
    float l  = x - hf;
    lo = (short)(__builtin_bit_cast(uint32_t, l) >> 16);
}

// ---------------------------------------------------------------------------
// Fully fused, barrier-light:
//   phase 1: QK^T -- q staged hi/lo in LDS once (1 barrier), k fragments read
//            DIRECTLY from global (row-major matches MFMA B layout) + cvt_pk.
//            Zero barriers in the 16-step K-loop -> deep load pipelining.
//   phase 2: softmax, P normalized in LDS sc (2 barriers).
//   phase 3: PV -- fp32 vraw staging only; B-fragments via strided ds_read_b32
//            + in-register cvt_pk hi/lo split (no vth/vtl, no transpose pass).
//            Column rotation (h + 8*((j>>3)&3)) & 127 -> ~2-way banks (free).
//            Register prefetch of next half overlaps MFMA. 16 barriers.
// LDS: union(q 33.3 KB, vraw 33.8 KB) + sc 8.4 KB = 42.2 KB.
// grid 448: b = id&63 (XCD affinity), i-tile = id>>6. 512 thr = 8 waves.
// ---------------------------------------------------------------------------
#define QST 520    // qhi/qlo row stride (shorts): 512 + 8 pad (2-way banks on b128)
#define VRS 132    // vraw row stride (floats): 128 + 4 pad

#define OFF_QLO 16640          // 16*520*2
#define POOLSZ  33792          // max(2*16640=33280, 64*132*4=33792)

__device__ inline void vload(const float* __restrict__ vb, int tid, int step,
                             f32x4 pf[4]) {
    const int half = step & 1, hb = (step >> 1) << 7;
    #pragma unroll
    for (int s = 0; s < 4; ++s) {
        const int f = tid + s * 512;
        const int j = f >> 5, h4 = (f & 31) << 2;
        const int jg = half * 64 + j;
        f32x4 x = {};
        if (jg < SEQ) x = *(const f32x4*)(vb + (size_t)jg * HID + hb + h4);
        pf[s] = x;
    }
}

__global__ __launch_bounds__(512, 4)
void fused_attn(const float* __restrict__ q, const float* __restrict__ k,
                const float* __restrict__ v, const float* __restrict__ aw,
                float* __restrict__ out, float* __restrict__ attn) {
    __shared__ __align__(16) char pool[POOLSZ];
    __shared__ __align__(16) float sc[16][132];
    short (*qhi)[QST]  = (short(*)[QST])(pool);
    short (*qlo)[QST]  = (short(*)[QST])(pool + OFF_QLO);
    float (*vraw)[VRS] = (float(*)[VRS])(pool);

    const int b   = blockIdx.x & 63;
    const int i0  = (blockIdx.x >> 6) * 16;
    const int tid = threadIdx.x;
    const int wv  = tid >> 6, lane = tid & 63;
    const int m   = lane & 15;
    const int g   = lane >> 4;
    const int kq  = g * 8;
    const int rq  = g * 4;
    const int j0w = wv * 16;

    const float* qb = q + (size_t)b * SEQ * HID;
    const float* kb = k + (size_t)b * SEQ * HID;
    const float* vb = v + (size_t)b * SEQ * HID;

    // ---------------- stage q hi/lo (once) ---------------------------------
    #pragma unroll
    for (int s = 0; s < 4; ++s) {
        const int f = tid + s * 512;
        const int r = f >> 7, c = (f & 127) << 2;
        const int gi = i0 + r;
        f32x4 x = {};
        if (gi < SEQ) x = *(const f32x4*)(qb + (size_t)gi * HID + c);
        short4 hv, lv;
        split_bf16(x[0], hv.x, lv.x);
        split_bf16(x[1], hv.y, lv.y);
        split_bf16(x[2], hv.z, lv.z);
        split_bf16(x[3], hv.w, lv.w);
        *(short4*)&qhi[r][c] = hv;
        *(short4*)&qlo[r][c] = lv;
    }
    __syncthreads();

    // ---------------- phase 1: QK^T, k direct from global, no barriers -----
    f32x4 acc = {};
    {
        const int jg = j0w + m;
        const int jr = (jg > NKQ) ? NKQ : jg;   // clamp; cols >100 of sc are junk, zeroed later
        const float* kr = kb + (size_t)jr * HID + kq;
        f32x4 k0 = *(const f32x4*)(kr);
        f32x4 k1 = *(const f32x4*)(kr + 4);
        #pragma unroll
        for (int ks = 0; ks < 16; ++ks) {
            f32x4 n0 = {}, n1 = {};
            if (ks < 15) {
                n0 = *(const f32x4*)(kr + (ks + 1) * 32);
                n1 = *(const f32x4*)(kr + (ks + 1) * 32 + 4);
            }
            u32x4 kp;
            kp[0] = cvt2(k0[0], k0[1]); kp[1] = cvt2(k0[2], k0[3]);
            kp[2] = cvt2(k1[0], k1[1]); kp[3] = cvt2(k1[2], k1[3]);
            const bf16x8 kH = __builtin_bit_cast(bf16x8, kp);
            const bf16x8 qH = *(const bf16x8*)&qhi[m][ks * 32 + kq];
            const bf16x8 qL = *(const bf16x8*)&qlo[m][ks * 32 + kq];
            acc = __builtin_amdgcn_mfma_f32_16x16x32_bf16(qH, kH, acc, 0, 0, 0);
            acc = __builtin_amdgcn_mfma_f32_16x16x32_bf16(qL, kH, acc, 0, 0, 0);
            k0 = n0; k1 = n1;
        }
    }
    #pragma unroll
    for (int r = 0; r < 4; ++r)
        sc[rq + r][j0w + m] = acc[r];
    __syncthreads();

    // ---------------- phase 2: softmax; normalized P stays in sc -----------
    {
        const int row = tid >> 5, t32 = tid & 31;
        const int gi  = i0 + row;
        float mx = -1e30f;
        for (int j = t32; j < SEQ; j += 32) {
            float s = sc[row][j] * INV_TEMP;
            sc[row][j] = s;
            mx = fmaxf(mx, s);
        }
        #pragma unroll
        for (int off = 1; off < 32; off <<= 1) mx = fmaxf(mx, __shfl_xor(mx, off));
        float sum = 0.f;
        for (int j = t32; j < SEQ; j += 32) {
            float e = __expf(sc[row][j] - mx);
            sc[row][j] = e;
            sum += e;
        }
        #pragma unroll
        for (int off = 1; off < 32; off <<= 1) sum += __shfl_xor(sum, off);
        const float inv = 1.f / sum;
        float* arow = attn + ((size_t)b * SEQ + gi) * SEQ;
        for (int j = t32; j < SEQ; j += 32) {
            float a = sc[row][j] * inv;
            sc[row][j] = a;                 // PV reads P from LDS
            if (gi < SEQ) arow[j] = a;      // tuple output
        }
        for (int j = SEQ + t32; j < 128; j += 32) sc[row][j] = 0.f;  // pad cols
    }
    __syncthreads();

    // ---------------- A fragments + class mask (hoisted) --------------------
    int ai = i0 + m; if (ai > NKQ) ai = NKQ;
    const int ci = ai / KCLS;
    uint32_t mbits = 0;
    #pragma unroll
    for (int ks = 0; ks < 4; ++ks)
        #pragma unroll
        for (int e = 0; e < 8; ++e)
            if (((ks * 32 + kq + e) / KCLS) == ci) mbits |= (1u << (ks * 8 + e));
    bf16x8 Ah[4], Al[4];
    #pragma unroll
    for (int ks = 0; ks < 4; ++ks) {
        const f32x4 u0 = *(const f32x4*)&sc[m][ks * 32 + kq];
        const f32x4 u1 = *(const f32x4*)&sc[m][ks * 32 + kq + 4];
        const float x[8] = {u0[0], u0[1], u0[2], u0[3], u1[0], u1[1], u1[2], u1[3]};
        #pragma unroll
        for (int e = 0; e < 8; ++e) {
            short h, l; split_bf16(x[e], h, l);
            Ah[ks][e] = h; Al[ks][e] = l;
        }
    }

    // ---------------- phase 3: PV + epilogue, 8 half-steps ------------------
    const int hl   = j0w + m;                  // local h (0..127) this lane owns
    const int rcol = (hl + 8 * g) & 127;       // rotation: matches write side
    f32x4 pf[4];
    vload(vb, tid, 0, pf);
    f32x4 T = {}, U = {};
    for (int step = 0; step < 8; ++step) {
        const int half = step & 1, hc = step >> 1;
        __syncthreads();                       // prev MFMA done -> vraw reusable
        #pragma unroll
        for (int s = 0; s < 4; ++s) {
            const int f = tid + s * 512;
            const int j = f >> 5, h4 = (f & 31) << 2;
            const int col = (h4 + 8 * ((j >> 3) & 3)) & 127;
            *(f32x4*)&vraw[j][col] = pf[s];
        }
        __syncthreads();                       // vraw ready
        if (step < 7) vload(vb, tid, step + 1, pf);   // overlap with MFMA

        #pragma unroll
        for (int ksl = 0; ksl < 2; ++ksl) {
            const int ks = half * 2 + ksl;
            const int jb = ksl * 32 + kq;
            u32x4 ph, pl;
            #pragma unroll
            for (int p = 0; p < 4; ++p) {
                const float x0 = vraw[jb + 2 * p][rcol];
                const float x1 = vraw[jb + 2 * p + 1][rcol];
                const uint32_t h01 = cvt2(x0, x1);
                const float r0 = x0 - __builtin_bit_cast(float, h01 << 16);
                const float r1 = x1 - __builtin_bit_cast(float, h01 & 0xFFFF0000u);
                ph[p] = h01;
                pl[p] = cvt2(r0, r1);
            }
            const bf16x8 Bh = __builtin_bit_cast(bf16x8, ph);
            const bf16x8 Bl = __builtin_bit_cast(bf16x8, pl);
            bf16x8 Mh;
            #pragma unroll
            for (int e = 0; e < 8; ++e)
                Mh[e] = (mbits & (1u << (ks * 8 + e))) ? Ah[ks][e] : (short)0;
            T = __builtin_amdgcn_mfma_f32_16x16x32_bf16(Ah[ks], Bh, T, 0, 0, 0);
            T = __builtin_amdgcn_mfma_f32_16x16x32_bf16(Ah[ks], Bl, T, 0, 0, 0);
            T = __builtin_amdgcn_mfma_f32_16x16x32_bf16(Al[ks], Bh, T, 0, 0, 0);
            U = __builtin_amdgcn_mfma_f32_16x16x32_bf16(Mh,     Bh, U, 0, 0, 0);
        }

        if (half == 1) {
            const int h = (hc << 7) + hl;
            const float w0 = aw[0 * HID + h], w1 = aw[1 * HID + h], w2 = aw[2 * HID + h];
            const float w3 = aw[3 * HID + h], w4 = aw[4 * HID + h], w5 = aw[5 * HID + h];
            const float vN = vb[(size_t)NKQ * HID + h];
            #pragma unroll
            for (int r = 0; r < 4; ++r) {
                const int i = i0 + rq + r;
                if (i >= SEQ) continue;
                const int il = rq + r;
                const float t = T[r], u = U[r];
                const float aiN = sc[il][NKQ];
                float o;
                if (i < NKQ) {
                    const float aii = sc[il][i];
                    const float vi  = vb[(size_t)i * HID + h];
                    o = w2 * t + (w1 - w2) * u + (w0 - w1) * aii * vi + (w3 - w2) * aiN * vN;
                } else {
                    o = w4 * t + (w5 - w4) * aiN * vN;
                }
                out[((size_t)b * SEQ + i) * HID + h] = o;
            }
            T = (f32x4){}; U = (f32x4){};
        }
    }
}

extern "C" void kernel_launch(void* const* d_in, const int* in_sizes, int n_in,
                              void* d_out, int out_size, void* d_ws, size_t ws_size,
                              hipStream_t stream) {
    const float* q  = (const float*)d_in[0];
    const float* k  = (const float*)d_in[1];
    const float* v  = (const float*)d_in[2];
    const float* aw = (const float*)d_in[3];
    float* out  = (float*)d_out;
    float* attn = out + (size_t)BATCH * SEQ * HID;   // tuple output: [out | attn]
    (void)d_ws; (void)ws_size;

    fused_attn<<<dim3(448), dim3(512), 0, stream>>>(q, k, v, aw, out, attn);
}

// Round 3
// 113.673 us; speedup vs baseline: 2.3397x; 2.3397x over previous
//
#include <hip/hip_runtime.h>
#include <math.h>
#include <stdint.h>

#define BATCH 64
#define SEQ   101
#define HID   512
#define NKQ   100      // N*K
#define KCLS  10
#define INV_TEMP 0.04419417382415922f   // 1/sqrt(512)

typedef short bf16x8 __attribute__((ext_vector_type(8)));
typedef float f32x4  __attribute__((ext_vector_type(4)));
typedef uint32_t u32x4 __attribute__((ext_vector_type(4)));

// HW packed f32->bf16 RNE: dst.lo = bf16(a), dst.hi = bf16(b)
__device__ inline uint32_t cvt2(float a, float b) {
    uint32_t r;
    asm("v_cvt_pk_bf16_f32 %0, %1, %2" : "=v"(r) : "v"(a), "v"(b));
    return r;
}
// truncation split: x == hi + lo to ~2^-17 rel (q & P planes)
__device__ inline void split_bf16(float x, short& hi, short& lo) {
    uint32_t u = __builtin_bit_cast(uint32_t, x);
    hi = (short)(u >> 16);
    float hf = __builtin_bit_cast(float, u & 0xFFFF0000u);
    float l  = x - hf;
    lo = (short)(__builtin_bit_cast(uint32_t, l) >> 16);
}

// ---------------------------------------------------------------------------
// Fully fused, barrier-light. Identical structure to round 2 EXCEPT the
// phase-3 step loop is now FULLY UNROLLED (#pragma unroll 8): round 2's
// runtime `step` made Ah[ks]/Al[ks]/pf[s] runtime-indexed -> scratch spills
// (WRITE_SIZE 75 MB of phantom traffic, 195 us). All indices are now
// compile-time constants so fragments stay in VGPRs (rule #20).
//   phase 1: QK^T -- q staged hi/lo in LDS once (1 barrier), k fragments read
//            DIRECTLY from global (row-major matches MFMA B layout) + cvt_pk.
//   phase 2: softmax, P normalized in LDS sc.
//   phase 3: PV -- fp32 vraw staging only; B-fragments via strided ds_read_b32
//            + in-register cvt_pk hi/lo split. Column rotation -> ~2-way banks.
//            Register prefetch of next half overlaps MFMA.
// LDS: union(q 33.3 KB, vraw 33.8 KB) + sc 8.4 KB = 42.2 KB.
// grid 448: b = id&63 (XCD affinity), i-tile = id>>6. 512 thr = 8 waves.
// ---------------------------------------------------------------------------
#define QST 520    // qhi/qlo row stride (shorts): 512 + 8 pad
#define VRS 132    // vraw row stride (floats): 128 + 4 pad

#define OFF_QLO 16640          // 16*520*2
#define POOLSZ  33792          // max(2*16640=33280, 64*132*4=33792)

__device__ inline void vload(const float* __restrict__ vb, int tid, int step,
                             f32x4 pf[4]) {
    const int half = step & 1, hb = (step >> 1) << 7;
    #pragma unroll
    for (int s = 0; s < 4; ++s) {
        const int f = tid + s * 512;
        const int j = f >> 5, h4 = (f & 31) << 2;
        const int jg = half * 64 + j;
        f32x4 x = {};
        if (jg < SEQ) x = *(const f32x4*)(vb + (size_t)jg * HID + hb + h4);
        pf[s] = x;
    }
}

__global__ __launch_bounds__(512, 4)
void fused_attn(const float* __restrict__ q, const float* __restrict__ k,
                const float* __restrict__ v, const float* __restrict__ aw,
                float* __restrict__ out, float* __restrict__ attn) {
    __shared__ __align__(16) char pool[POOLSZ];
    __shared__ __align__(16) float sc[16][132];
    short (*qhi)[QST]  = (short(*)[QST])(pool);
    short (*qlo)[QST]  = (short(*)[QST])(pool + OFF_QLO);
    float (*vraw)[VRS] = (float(*)[VRS])(pool);

    const int b   = blockIdx.x & 63;
    const int i0  = (blockIdx.x >> 6) * 16;
    const int tid = threadIdx.x;
    const int wv  = tid >> 6, lane = tid & 63;
    const int m   = lane & 15;
    const int g   = lane >> 4;
    const int kq  = g * 8;
    const int rq  = g * 4;
    const int j0w = wv * 16;

    const float* qb = q + (size_t)b * SEQ * HID;
    const float* kb = k + (size_t)b * SEQ * HID;
    const float* vb = v + (size_t)b * SEQ * HID;

    // ---------------- stage q hi/lo (once) ---------------------------------
    #pragma unroll
    for (int s = 0; s < 4; ++s) {
        const int f = tid + s * 512;
        const int r = f >> 7, c = (f & 127) << 2;
        const int gi = i0 + r;
        f32x4 x = {};
        if (gi < SEQ) x = *(const f32x4*)(qb + (size_t)gi * HID + c);
        short4 hv, lv;
        split_bf16(x[0], hv.x, lv.x);
        split_bf16(x[1], hv.y, lv.y);
        split_bf16(x[2], hv.z, lv.z);
        split_bf16(x[3], hv.w, lv.w);
        *(short4*)&qhi[r][c] = hv;
        *(short4*)&qlo[r][c] = lv;
    }
    __syncthreads();

    // ---------------- phase 1: QK^T, k direct from global, no barriers -----
    f32x4 acc = {};
    {
        const int jg = j0w + m;
        const int jr = (jg > NKQ) ? NKQ : jg;   // clamp; junk cols zeroed later
        const float* kr = kb + (size_t)jr * HID + kq;
        f32x4 k0 = *(const f32x4*)(kr);
        f32x4 k1 = *(const f32x4*)(kr + 4);
        #pragma unroll
        for (int ks = 0; ks < 16; ++ks) {
            f32x4 n0 = {}, n1 = {};
            if (ks < 15) {
                n0 = *(const f32x4*)(kr + (ks + 1) * 32);
                n1 = *(const f32x4*)(kr + (ks + 1) * 32 + 4);
            }
            u32x4 kp;
            kp[0] = cvt2(k0[0], k0[1]); kp[1] = cvt2(k0[2], k0[3]);
            kp[2] = cvt2(k1[0], k1[1]); kp[3] = cvt2(k1[2], k1[3]);
            const bf16x8 kH = __builtin_bit_cast(bf16x8, kp);
            const bf16x8 qH = *(const bf16x8*)&qhi[m][ks * 32 + kq];
            const bf16x8 qL = *(const bf16x8*)&qlo[m][ks * 32 + kq];
            acc = __builtin_amdgcn_mfma_f32_16x16x32_bf16(qH, kH, acc, 0, 0, 0);
            acc = __builtin_amdgcn_mfma_f32_16x16x32_bf16(qL, kH, acc, 0, 0, 0);
            k0 = n0; k1 = n1;
        }
    }
    #pragma unroll
    for (int r = 0; r < 4; ++r)
        sc[rq + r][j0w + m] = acc[r];
    __syncthreads();

    // ---------------- phase 2: softmax; normalized P stays in sc -----------
    {
        const int row = tid >> 5, t32 = tid & 31;
        const int gi  = i0 + row;
        float mx = -1e30f;
        for (int j = t32; j < SEQ; j += 32) {
            float s = sc[row][j] * INV_TEMP;
            sc[row][j] = s;
            mx = fmaxf(mx, s);
        }
        #pragma unroll
        for (int off = 1; off < 32; off <<= 1) mx = fmaxf(mx, __shfl_xor(mx, off));
        float sum = 0.f;
        for (int j = t32; j < SEQ; j += 32) {
            float e = __expf(sc[row][j] - mx);
            sc[row][j] = e;
            sum += e;
        }
        #pragma unroll
        for (int off = 1; off < 32; off <<= 1) sum += __shfl_xor(sum, off);
        const float inv = 1.f / sum;
        float* arow = attn + ((size_t)b * SEQ + gi) * SEQ;
        for (int j = t32; j < SEQ; j += 32) {
            float a = sc[row][j] * inv;
            sc[row][j] = a;                 // PV reads P from LDS
            if (gi < SEQ) arow[j] = a;      // tuple output
        }
        for (int j = SEQ + t32; j < 128; j += 32) sc[row][j] = 0.f;  // pad cols
    }
    __syncthreads();

    // ---------------- A fragments + class mask (hoisted) --------------------
    int ai = i0 + m; if (ai > NKQ) ai = NKQ;
    const int ci = ai / KCLS;
    uint32_t mbits = 0;
    #pragma unroll
    for (int ks = 0; ks < 4; ++ks)
        #pragma unroll
        for (int e = 0; e < 8; ++e)
            if (((ks * 32 + kq + e) / KCLS) == ci) mbits |= (1u << (ks * 8 + e));
    bf16x8 Ah[4], Al[4];
    #pragma unroll
    for (int ks = 0; ks < 4; ++ks) {
        const f32x4 u0 = *(const f32x4*)&sc[m][ks * 32 + kq];
        const f32x4 u1 = *(const f32x4*)&sc[m][ks * 32 + kq + 4];
        const float x[8] = {u0[0], u0[1], u0[2], u0[3], u1[0], u1[1], u1[2], u1[3]};
        #pragma unroll
        for (int e = 0; e < 8; ++e) {
            short h, l; split_bf16(x[e], h, l);
            Ah[ks][e] = h; Al[ks][e] = l;
        }
    }

    // ---------------- phase 3: PV + epilogue, 8 half-steps (FULL UNROLL) ----
    const int hl   = j0w + m;                  // local h (0..127) this lane owns
    const int rcol = (hl + 8 * g) & 127;       // rotation: matches write side
    f32x4 pf[4];
    vload(vb, tid, 0, pf);
    f32x4 T = {}, U = {};
    #pragma unroll 8
    for (int step = 0; step < 8; ++step) {     // unrolled -> all idx static
        const int half = step & 1, hc = step >> 1;
        __syncthreads();                       // prev MFMA done -> vraw reusable
        #pragma unroll
        for (int s = 0; s < 4; ++s) {
            const int f = tid + s * 512;
            const int j = f >> 5, h4 = (f & 31) << 2;
            const int col = (h4 + 8 * ((j >> 3) & 3)) & 127;
            *(f32x4*)&vraw[j][col] = pf[s];
        }
        __syncthreads();                       // vraw ready
        if (step < 7) vload(vb, tid, step + 1, pf);   // overlap with MFMA

        #pragma unroll
        for (int ksl = 0; ksl < 2; ++ksl) {
            const int ks = half * 2 + ksl;
            const int jb = ksl * 32 + kq;
            u32x4 ph, pl;
            #pragma unroll
            for (int p = 0; p < 4; ++p) {
                const float x0 = vraw[jb + 2 * p][rcol];
                const float x1 = vraw[jb + 2 * p + 1][rcol];
                const uint32_t h01 = cvt2(x0, x1);
                const float r0 = x0 - __builtin_bit_cast(float, h01 << 16);
                const float r1 = x1 - __builtin_bit_cast(float, h01 & 0xFFFF0000u);
                ph[p] = h01;
                pl[p] = cvt2(r0, r1);
            }
            const bf16x8 Bh = __builtin_bit_cast(bf16x8, ph);
            const bf16x8 Bl = __builtin_bit_cast(bf16x8, pl);
            bf16x8 Mh;
            #pragma unroll
            for (int e = 0; e < 8; ++e)
                Mh[e] = (mbits & (1u << (ks * 8 + e))) ? Ah[ks][e] : (short)0;
            T = __builtin_amdgcn_mfma_f32_16x16x32_bf16(Ah[ks], Bh, T, 0, 0, 0);
            T = __builtin_amdgcn_mfma_f32_16x16x32_bf16(Ah[ks], Bl, T, 0, 0, 0);
            T = __builtin_amdgcn_mfma_f32_16x16x32_bf16(Al[ks], Bh, T, 0, 0, 0);
            U = __builtin_amdgcn_mfma_f32_16x16x32_bf16(Mh,     Bh, U, 0, 0, 0);
        }

        if (half == 1) {
            const int h = (hc << 7) + hl;
            const float w0 = aw[0 * HID + h], w1 = aw[1 * HID + h], w2 = aw[2 * HID + h];
            const float w3 = aw[3 * HID + h], w4 = aw[4 * HID + h], w5 = aw[5 * HID + h];
            const float vN = vb[(size_t)NKQ * HID + h];
            #pragma unroll
            for (int r = 0; r < 4; ++r) {
                const int i = i0 + rq + r;
                if (i >= SEQ) continue;
                const int il = rq + r;
                const float t = T[r], u = U[r];
                const float aiN = sc[il][NKQ];
                float o;
                if (i < NKQ) {
                    const float aii = sc[il][i];
                    const float vi  = vb[(size_t)i * HID + h];
                    o = w2 * t + (w1 - w2) * u + (w0 - w1) * aii * vi + (w3 - w2) * aiN * vN;
                } else {
                    o = w4 * t + (w5 - w4) * aiN * vN;
                }
                out[((size_t)b * SEQ + i) * HID + h] = o;
            }
            T = (f32x4){}; U = (f32x4){};
        }
    }
}

extern "C" void kernel_launch(void* const* d_in, const int* in_sizes, int n_in,
                              void* d_out, int out_size, void* d_ws, size_t ws_size,
                              hipStream_t stream) {
    const float* q  = (const float*)d_in[0];
    const float* k  = (const float*)d_in[1];
    const float* v  = (const float*)d_in[2];
    const float* aw = (const float*)d_in[3];
    float* out  = (float*)d_out;
    float* attn = out + (size_t)BATCH * SEQ * HID;   // tuple output: [out | attn]
    (void)d_ws; (void)ws_size;

    fused_attn<<<dim3(448), dim3(512), 0, stream>>>(q, k, v, aw, out, attn);
}

// Round 4
// 110.951 us; speedup vs baseline: 2.3971x; 1.0245x over previous
//
#include <hip/hip_runtime.h>
#include <math.h>
#include <stdint.h>

#define BATCH 64
#define SEQ   101
#define HID   512
#define NKQ   100      // N*K
#define KCLS  10
#define INV_TEMP 0.04419417382415922f   // 1/sqrt(512)

typedef short bf16x8 __attribute__((ext_vector_type(8)));
typedef float f32x4  __attribute__((ext_vector_type(4)));
typedef uint32_t u32x4 __attribute__((ext_vector_type(4)));

// HW packed f32->bf16 RNE: dst.lo = bf16(a), dst.hi = bf16(b)
__device__ inline uint32_t cvt2(float a, float b) {
    uint32_t r;
    asm("v_cvt_pk_bf16_f32 %0, %1, %2" : "=v"(r) : "v"(a), "v"(b));
    return r;
}
// truncation split: x == hi + lo to ~2^-17 rel (q & P planes)
__device__ inline void split_bf16(float x, short& hi, short& lo) {
    uint32_t u = __builtin_bit_cast(uint32_t, x);
    hi = (short)(u >> 16);
    float hf = __builtin_bit_cast(float, u & 0xFFFF0000u);
    float l  = x - hf;
    lo = (short)(__builtin_bit_cast(uint32_t, l) >> 16);
}

// ---------------------------------------------------------------------------
// Fully fused, 3 barriers total.
//   phase 1: QK^T -- q staged hi/lo in LDS once (1 barrier), k fragments read
//            DIRECTLY from global (row-major matches MFMA B layout) + cvt_pk.
//            Zero barriers in the 16-step K-loop.
//   phase 2: softmax, P normalized in LDS sc (2 barriers).
//   phase 3: PV -- ZERO barriers, ZERO LDS. B-fragment element e for lane
//            (m,g) is V[ks*32+g*8+e][hc*128+hl]; for fixed e the 16 lanes of
//            a g-group read 16 consecutive floats (64B coalesced segment),
//            and V (207 KB/batch) is L2-resident across the 7 same-b blocks
//            on the same XCD (ids differ by 64 = 0 mod 8). hi/lo split done
//            in-register via cvt_pk. Rows j>100 clamp to 100 (P=0 there).
// LDS: q hi/lo 32.5 KB + sc 8.4 KB = 40.9 KB.
// grid 448: b = id&63 (XCD affinity), i-tile = id>>6. 512 thr = 8 waves.
// ---------------------------------------------------------------------------
#define QST 520    // qhi/qlo row stride (shorts): 512 + 8 pad

#define OFF_QLO 16640          // 16*520*2
#define POOLSZ  33280          // 2*16640

__global__ __launch_bounds__(512, 4)
void fused_attn(const float* __restrict__ q, const float* __restrict__ k,
                const float* __restrict__ v, const float* __restrict__ aw,
                float* __restrict__ out, float* __restrict__ attn) {
    __shared__ __align__(16) char pool[POOLSZ];
    __shared__ __align__(16) float sc[16][132];
    short (*qhi)[QST] = (short(*)[QST])(pool);
    short (*qlo)[QST] = (short(*)[QST])(pool + OFF_QLO);

    const int b   = blockIdx.x & 63;
    const int i0  = (blockIdx.x >> 6) * 16;
    const int tid = threadIdx.x;
    const int wv  = tid >> 6, lane = tid & 63;
    const int m   = lane & 15;
    const int g   = lane >> 4;
    const int kq  = g * 8;
    const int rq  = g * 4;
    const int j0w = wv * 16;

    const float* qb = q + (size_t)b * SEQ * HID;
    const float* kb = k + (size_t)b * SEQ * HID;
    const float* vb = v + (size_t)b * SEQ * HID;

    // ---------------- stage q hi/lo (once) ---------------------------------
    #pragma unroll
    for (int s = 0; s < 4; ++s) {
        const int f = tid + s * 512;
        const int r = f >> 7, c = (f & 127) << 2;
        const int gi = i0 + r;
        f32x4 x = {};
        if (gi < SEQ) x = *(const f32x4*)(qb + (size_t)gi * HID + c);
        short4 hv, lv;
        split_bf16(x[0], hv.x, lv.x);
        split_bf16(x[1], hv.y, lv.y);
        split_bf16(x[2], hv.z, lv.z);
        split_bf16(x[3], hv.w, lv.w);
        *(short4*)&qhi[r][c] = hv;
        *(short4*)&qlo[r][c] = lv;
    }
    __syncthreads();

    // ---------------- phase 1: QK^T, k direct from global, no barriers -----
    f32x4 acc = {};
    {
        const int jg = j0w + m;
        const int jr = (jg > NKQ) ? NKQ : jg;   // clamp; junk cols zeroed later
        const float* kr = kb + (size_t)jr * HID + kq;
        f32x4 k0 = *(const f32x4*)(kr);
        f32x4 k1 = *(const f32x4*)(kr + 4);
        #pragma unroll
        for (int ks = 0; ks < 16; ++ks) {
            f32x4 n0 = {}, n1 = {};
            if (ks < 15) {
                n0 = *(const f32x4*)(kr + (ks + 1) * 32);
                n1 = *(const f32x4*)(kr + (ks + 1) * 32 + 4);
            }
            u32x4 kp;
            kp[0] = cvt2(k0[0], k0[1]); kp[1] = cvt2(k0[2], k0[3]);
            kp[2] = cvt2(k1[0], k1[1]); kp[3] = cvt2(k1[2], k1[3]);
            const bf16x8 kH = __builtin_bit_cast(bf16x8, kp);
            const bf16x8 qH = *(const bf16x8*)&qhi[m][ks * 32 + kq];
            const bf16x8 qL = *(const bf16x8*)&qlo[m][ks * 32 + kq];
            acc = __builtin_amdgcn_mfma_f32_16x16x32_bf16(qH, kH, acc, 0, 0, 0);
            acc = __builtin_amdgcn_mfma_f32_16x16x32_bf16(qL, kH, acc, 0, 0, 0);
            k0 = n0; k1 = n1;
        }
    }
    #pragma unroll
    for (int r = 0; r < 4; ++r)
        sc[rq + r][j0w + m] = acc[r];
    __syncthreads();

    // ---------------- phase 2: softmax; normalized P stays in sc -----------
    {
        const int row = tid >> 5, t32 = tid & 31;
        const int gi  = i0 + row;
        float mx = -1e30f;
        for (int j = t32; j < SEQ; j += 32) {
            float s = sc[row][j] * INV_TEMP;
            sc[row][j] = s;
            mx = fmaxf(mx, s);
        }
        #pragma unroll
        for (int off = 1; off < 32; off <<= 1) mx = fmaxf(mx, __shfl_xor(mx, off));
        float sum = 0.f;
        for (int j = t32; j < SEQ; j += 32) {
            float e = __expf(sc[row][j] - mx);
            sc[row][j] = e;
            sum += e;
        }
        #pragma unroll
        for (int off = 1; off < 32; off <<= 1) sum += __shfl_xor(sum, off);
        const float inv = 1.f / sum;
        float* arow = attn + ((size_t)b * SEQ + gi) * SEQ;
        for (int j = t32; j < SEQ; j += 32) {
            float a = sc[row][j] * inv;
            sc[row][j] = a;                 // PV reads P from LDS
            if (gi < SEQ) arow[j] = a;      // tuple output
        }
        for (int j = SEQ + t32; j < 128; j += 32) sc[row][j] = 0.f;  // pad cols
    }
    __syncthreads();

    // ---------------- A fragments + class mask (hoisted) --------------------
    int ai = i0 + m; if (ai > NKQ) ai = NKQ;
    const int ci = ai / KCLS;
    uint32_t mbits = 0;
    #pragma unroll
    for (int ks = 0; ks < 4; ++ks)
        #pragma unroll
        for (int e = 0; e < 8; ++e)
            if (((ks * 32 + kq + e) / KCLS) == ci) mbits |= (1u << (ks * 8 + e));
    bf16x8 Ah[4], Al[4];
    #pragma unroll
    for (int ks = 0; ks < 4; ++ks) {
        const f32x4 u0 = *(const f32x4*)&sc[m][ks * 32 + kq];
        const f32x4 u1 = *(const f32x4*)&sc[m][ks * 32 + kq + 4];
        const float x[8] = {u0[0], u0[1], u0[2], u0[3], u1[0], u1[1], u1[2], u1[3]};
        #pragma unroll
        for (int e = 0; e < 8; ++e) {
            short h, l; split_bf16(x[e], h, l);
            Ah[ks][e] = h; Al[ks][e] = l;
        }
    }

    // ---------------- phase 3: PV direct-from-global, no barriers -----------
    const int hl = j0w + m;                    // local h (0..127) this lane owns
    for (int hc = 0; hc < 4; ++hc) {
        const int h = (hc << 7) + hl;
        const float* vh = vb + h;
        f32x4 T = {}, U = {};
        #pragma unroll
        for (int ks = 0; ks < 4; ++ks) {
            float xv[8];
            #pragma unroll
            for (int e = 0; e < 8; ++e) {
                const int j  = ks * 32 + kq + e;
                const int jr = (j > NKQ) ? NKQ : j;   // P=0 for j>100 nullifies
                xv[e] = vh[(size_t)jr * HID];
            }
            u32x4 ph, pl;
            #pragma unroll
            for (int p = 0; p < 4; ++p) {
                const uint32_t h01 = cvt2(xv[2 * p], xv[2 * p + 1]);
                const float r0 = xv[2 * p]     - __builtin_bit_cast(float, h01 << 16);
                const float r1 = xv[2 * p + 1] - __builtin_bit_cast(float, h01 & 0xFFFF0000u);
                ph[p] = h01;
                pl[p] = cvt2(r0, r1);
            }
            const bf16x8 Bh = __builtin_bit_cast(bf16x8, ph);
            const bf16x8 Bl = __builtin_bit_cast(bf16x8, pl);
            bf16x8 Mh;
            #pragma unroll
            for (int e = 0; e < 8; ++e)
                Mh[e] = (mbits & (1u << (ks * 8 + e))) ? Ah[ks][e] : (short)0;
            T = __builtin_amdgcn_mfma_f32_16x16x32_bf16(Ah[ks], Bh, T, 0, 0, 0);
            T = __builtin_amdgcn_mfma_f32_16x16x32_bf16(Ah[ks], Bl, T, 0, 0, 0);
            T = __builtin_amdgcn_mfma_f32_16x16x32_bf16(Al[ks], Bh, T, 0, 0, 0);
            U = __builtin_amdgcn_mfma_f32_16x16x32_bf16(Mh,     Bh, U, 0, 0, 0);
        }
        // epilogue for this h-chunk
        const float w0 = aw[0 * HID + h], w1 = aw[1 * HID + h], w2 = aw[2 * HID + h];
        const float w3 = aw[3 * HID + h], w4 = aw[4 * HID + h], w5 = aw[5 * HID + h];
        const float vN = vb[(size_t)NKQ * HID + h];
        #pragma unroll
        for (int r = 0; r < 4; ++r) {
            const int i = i0 + rq + r;
            if (i >= SEQ) continue;
            const int il = rq + r;
            const float t = T[r], u = U[r];
            const float aiN = sc[il][NKQ];
            float o;
            if (i < NKQ) {
                const float aii = sc[il][i];
                const float vi  = vb[(size_t)i * HID + h];
                o = w2 * t + (w1 - w2) * u + (w0 - w1) * aii * vi + (w3 - w2) * aiN * vN;
            } else {
                o = w4 * t + (w5 - w4) * aiN * vN;
            }
            out[((size_t)b * SEQ + i) * HID + h] = o;
        }
    }
}

extern "C" void kernel_launch(void* const* d_in, const int* in_sizes, int n_in,
                              void* d_out, int out_size, void* d_ws, size_t ws_size,
                              hipStream_t stream) {
    const float* q  = (const float*)d_in[0];
    const float* k  = (const float*)d_in[1];
    const float* v  = (const float*)d_in[2];
    const float* aw = (const float*)d_in[3];
    float* out  = (float*)d_out;
    float* attn = out + (size_t)BATCH * SEQ * HID;   // tuple output: [out | attn]
    (void)d_ws; (void)ws_size;

    fused_attn<<<dim3(448), dim3(512), 0, stream>>>(q, k, v, aw, out, attn);
}